// Round 9
// baseline (844.400 us; speedup 1.0000x reference)
//
#include <hip/hip_runtime.h>

#define N_NODES 239616
#define NLM 468
#define BSZ 512
#define NEDGE 3833856
#define IN_C 64
#define OUT_C 128
#define KW 3
#define EPSV 1e-5f

#define GM 128      // nodes per gemm1 block (MFMA tile M)
#define GN 64       // nodes per final block
#define LCH 64      // L-rows per conv block
#define NCH 8       // ceil(468/64)
#define NPASS 8     // XCD count; dst-range classes in k_fill
#define FILLB 2048  // k_fill grid (fully resident -> bid%8 == XCD holds)

typedef __attribute__((ext_vector_type(8))) __bf16 bf16x8;
typedef __attribute__((ext_vector_type(4))) float f32x4;
typedef __attribute__((ext_vector_type(4))) int i32x4;

__device__ inline unsigned short f2bf(float f) {
    unsigned int u = __builtin_bit_cast(unsigned int, f);
    u = (u + 0x7FFFu + ((u >> 16) & 1u)) >> 16;
    return (unsigned short)u;
}

// ================= CSR build (counting sort by dst) =================

__global__ __launch_bounds__(256) void k_hist(const int* __restrict__ ei,
                                              int* __restrict__ hist) {
    int e = blockIdx.x * 256 + threadIdx.x;   // E threads
    int d = __builtin_nontemporal_load(ei + NEDGE + e);
    atomicAdd(&hist[d], 1);
}

__global__ __launch_bounds__(256) void k_scan1(const int* __restrict__ hist,
                                               int* __restrict__ off,
                                               int* __restrict__ btot) {
    __shared__ int ts[256];
    int base = blockIdx.x * 1024 + threadIdx.x * 4;
    int4 v = *reinterpret_cast<const int4*>(hist + base);
    int s = v.x + v.y + v.z + v.w;
    ts[threadIdx.x] = s;
    __syncthreads();
    for (int d = 1; d < 256; d <<= 1) {
        int t = (threadIdx.x >= d) ? ts[threadIdx.x - d] : 0;
        __syncthreads();
        ts[threadIdx.x] += t;
        __syncthreads();
    }
    int excl = ts[threadIdx.x] - s;
    int4 o;
    o.x = excl; o.y = excl + v.x; o.z = o.y + v.y; o.w = o.z + v.z;
    *reinterpret_cast<int4*>(off + base) = o;
    if (threadIdx.x == 255) btot[blockIdx.x] = ts[255];
}

__global__ void k_scan2(int* __restrict__ btot) {
    __shared__ int ts[256];
    int v = (threadIdx.x < (N_NODES / 1024)) ? btot[threadIdx.x] : 0;
    ts[threadIdx.x] = v;
    __syncthreads();
    for (int d = 1; d < 256; d <<= 1) {
        int t = (threadIdx.x >= d) ? ts[threadIdx.x - d] : 0;
        __syncthreads();
        ts[threadIdx.x] += t;
        __syncthreads();
    }
    if (threadIdx.x < (N_NODES / 1024)) btot[threadIdx.x] = ts[threadIdx.x] - v;
}

__global__ __launch_bounds__(256) void k_scan3(int* __restrict__ off,
                                               const int* __restrict__ btot,
                                               int* __restrict__ cur) {
    int i = blockIdx.x * 256 + threadIdx.x;   // N threads
    int v = off[i] + btot[i >> 10];
    off[i] = v;
    cur[i] = v;
}

// XCD-ranged fill with non-temporal edge streaming: dirty elist lines stay
// in L2 until all ~16 slot-writes land -> full-line writebacks.
__global__ __launch_bounds__(256) void k_fill(const int* __restrict__ ei,
                                              int* __restrict__ cur,
                                              int* __restrict__ elist) {
    const int pass = blockIdx.x & 7;
    const int lo = pass * (N_NODES / NPASS);
    const int hi = lo + (N_NODES / NPASS);
    const int tid = (blockIdx.x >> 3) * 256 + threadIdx.x;   // 0..65535
    const int stride = (FILLB / NPASS) * 256;                // 65536
    const int E4 = NEDGE / 4;
    const i32x4* dpt = reinterpret_cast<const i32x4*>(ei + NEDGE);
    const i32x4* spt = reinterpret_cast<const i32x4*>(ei);
    for (int i = tid; i < E4; i += stride) {
        i32x4 d4 = __builtin_nontemporal_load(dpt + i);
        bool m0 = (d4[0] >= lo && d4[0] < hi);
        bool m1 = (d4[1] >= lo && d4[1] < hi);
        bool m2 = (d4[2] >= lo && d4[2] < hi);
        bool m3 = (d4[3] >= lo && d4[3] < hi);
        if (!(m0 | m1 | m2 | m3)) continue;
        i32x4 s4 = __builtin_nontemporal_load(spt + i);
        if (m0) elist[atomicAdd(&cur[d4[0]], 1)] = s4[0];
        if (m1) elist[atomicAdd(&cur[d4[1]], 1)] = s4[1];
        if (m2) elist[atomicAdd(&cur[d4[2]], 1)] = s4[2];
        if (m3) elist[atomicAdd(&cur[d4[3]], 1)] = s4[3];
    }
}

__global__ __launch_bounds__(256) void k_gather(const float* __restrict__ x,
                                                const int* __restrict__ off,
                                                const int* __restrict__ hist,
                                                const int* __restrict__ elist,
                                                float* __restrict__ agg) {
    int t = blockIdx.x * 256 + threadIdx.x;   // N*16 threads
    int n  = t >> 4;
    int j4 = (t & 15) << 2;
    int start = off[n];
    int deg   = hist[n];
    float4 acc = make_float4(0.f, 0.f, 0.f, 0.f);
    for (int i = 0; i < deg; ++i) {
        int s = __builtin_nontemporal_load(elist + start + i);
        float4 v = *reinterpret_cast<const float4*>(x + (size_t)s * IN_C + j4);
        acc.x += v.x; acc.y += v.y; acc.z += v.z; acc.w += v.w;
    }
    *reinterpret_cast<float4*>(agg + (size_t)n * IN_C + j4) = acc;
}

// --- pack Wcat = [W_rel; W_root] (128x128, k-major) -> bf16 B-fragments [4][8][64][8] ---
__global__ __launch_bounds__(256) void k_wprep2(const float* __restrict__ Wrel,
                                                const float* __restrict__ Wroot,
                                                unsigned short* __restrict__ wG) {
    int i = blockIdx.x * 256 + threadIdx.x;   // 16384 threads
    int j    = i & 7;
    int lane = (i >> 3) & 63;
    int g    = (i >> 9) & 7;
    int ks   = i >> 12;
    int o    = g * 16 + (lane & 15);
    int k    = ks * 32 + ((lane >> 4) << 3) + j;
    float v = (k < IN_C) ? Wrel[k * OUT_C + o] : Wroot[(k - IN_C) * OUT_C + o];
    wG[i] = f2bf(v);
}

// ======== h = [agg||x] @ Wcat + b_rel via bf16 MFMA, fused BN1 stats ========
__global__ __launch_bounds__(256) void k_gemm1(const float* __restrict__ agg,
                                               const float* __restrict__ x,
                                               const unsigned short* __restrict__ wG,
                                               const float* __restrict__ brel,
                                               float* __restrict__ h,
                                               float* __restrict__ sums) {
    __shared__ unsigned short tile[GM * 128];   // bf16 A-tile, XOR-swizzled, 32 KB
    __shared__ float red[2][OUT_C];
    const int n0 = blockIdx.x * GM;

    for (int i = threadIdx.x; i < 2 * OUT_C; i += 256) (&red[0][0])[i] = 0.f;

    for (int i = threadIdx.x; i < GM * 16; i += 256) {
        int t = i >> 4, s = i & 15;
        const float* src = (s < 8) ? (agg + (size_t)(n0 + t) * IN_C + s * 8)
                                   : (x   + (size_t)(n0 + t) * IN_C + (s - 8) * 8);
        float4 f0 = *reinterpret_cast<const float4*>(src);
        float4 f1 = *reinterpret_cast<const float4*>(src + 4);
        uint4 u;
        u.x = f2bf(f0.x) | ((unsigned)f2bf(f0.y) << 16);
        u.y = f2bf(f0.z) | ((unsigned)f2bf(f0.w) << 16);
        u.z = f2bf(f1.x) | ((unsigned)f2bf(f1.y) << 16);
        u.w = f2bf(f1.z) | ((unsigned)f2bf(f1.w) << 16);
        int byte = t * 256 + (((s ^ (t & 7)) & 15) << 4);
        *reinterpret_cast<uint4*>(reinterpret_cast<char*>(tile) + byte) = u;
    }
    __syncthreads();

    const int w    = threadIdx.x >> 6;    // wave -> rows [32w, 32w+32)
    const int lane = threadIdx.x & 63;
    const int r16  = lane & 15;
    const int kg   = lane >> 4;           // 0..3

    f32x4 acc[2][8];
    #pragma unroll
    for (int rs = 0; rs < 2; ++rs)
        #pragma unroll
        for (int g = 0; g < 8; ++g)
            acc[rs][g] = (f32x4){0.f, 0.f, 0.f, 0.f};

    for (int ks = 0; ks < 4; ++ks) {
        bf16x8 a[2];
        #pragma unroll
        for (int rs = 0; rs < 2; ++rs) {
            const int t = w * 32 + rs * 16 + r16;
            const int slot = ks * 4 + kg;
            const int byte = t * 256 + (((slot ^ (t & 7)) & 15) << 4);
            uint4 u = *reinterpret_cast<const uint4*>(reinterpret_cast<const char*>(tile) + byte);
            a[rs] = __builtin_bit_cast(bf16x8, u);
        }
        #pragma unroll
        for (int g = 0; g < 8; ++g) {
            uint4 u = *reinterpret_cast<const uint4*>(wG + (((ks * 8 + g) * 64 + lane) << 3));
            bf16x8 b = __builtin_bit_cast(bf16x8, u);
            acc[0][g] = __builtin_amdgcn_mfma_f32_16x16x32_bf16(a[0], b, acc[0][g], 0, 0, 0);
            acc[1][g] = __builtin_amdgcn_mfma_f32_16x16x32_bf16(a[1], b, acc[1][g], 0, 0, 0);
        }
    }

    #pragma unroll
    for (int g = 0; g < 8; ++g) {
        const int col = g * 16 + r16;
        const float bias = brel[col];
        float s = 0.f, q = 0.f;
        #pragma unroll
        for (int rs = 0; rs < 2; ++rs) {
            #pragma unroll
            for (int reg = 0; reg < 4; ++reg) {
                const int row = n0 + w * 32 + rs * 16 + kg * 4 + reg;
                float v = acc[rs][g][reg] + bias;
                h[(size_t)row * OUT_C + col] = v;
                s += v;
                q += v * v;
            }
        }
        atomicAdd(&red[0][col], s);
        atomicAdd(&red[1][col], q);
    }
    __syncthreads();
    if (threadIdx.x < OUT_C) {
        atomicAdd(&sums[threadIdx.x], red[0][threadIdx.x]);
        atomicAdd(&sums[OUT_C + threadIdx.x], red[1][threadIdx.x]);
    }
}

// ---------------- BN scale/shift from sums ----------------
__global__ void k_bnparams(const float* __restrict__ sums,
                           const float* __restrict__ g,
                           const float* __restrict__ b,
                           float* __restrict__ sc, float* __restrict__ sh) {
    int c = threadIdx.x;   // 128 threads
    const float inv_n = 1.0f / (float)N_NODES;
    float mean = sums[c] * inv_n;
    float var  = sums[OUT_C + c] * inv_n - mean * mean;
    float s = g[c] * rsqrtf(var + EPSV);
    sc[c] = s;
    sh[c] = b[c] - mean * s;
}

// ---------------- transpose res_w [128][64] -> rwT [64][128] ----------------
__global__ __launch_bounds__(256) void k_trw(const float* __restrict__ rw,
                                             float* __restrict__ rwT) {
    int i = blockIdx.x * 256 + threadIdx.x;   // 8192 threads
    int o = i >> 6;
    int k = i & 63;
    rwT[k * OUT_C + o] = rw[i];
}

// ----- pack conv_w [O][CI][KW] f32 -> bf16 B-fragments [12][8][64][8] -----
__global__ __launch_bounds__(256) void k_wprep(const float* __restrict__ w,
                                               unsigned short* __restrict__ wBf) {
    int i = blockIdx.x * 256 + threadIdx.x;   // 49152 threads
    int j    = i & 7;
    int lane = (i >> 3) & 63;
    int g    = (i >> 9) & 7;
    int ks   = i >> 12;
    int o    = g * 16 + (lane & 15);
    int ci   = (ks & 3) * 32 + ((lane >> 4) << 3) + j;
    int ktap = ks >> 2;
    wBf[i] = f2bf(w[o * (OUT_C * KW) + ci * KW + ktap]);
}

// ------- Conv1d via bf16 MFMA: BN1+ReLU fused at staging, BN2 stats fused -------
__global__ __launch_bounds__(256) void k_conv(const float* __restrict__ h1,
                                              const unsigned short* __restrict__ wBf,
                                              const float* __restrict__ cb,
                                              const float* __restrict__ sc,
                                              const float* __restrict__ sh,
                                              float* __restrict__ out,
                                              float* __restrict__ sums) {
    __shared__ unsigned short tile[(LCH + 2) * OUT_C];   // bf16, XOR-swizzled, 16.9 KB
    __shared__ float red[2][OUT_C];
    const int b  = blockIdx.x >> 3;
    const int ch = blockIdx.x & 7;
    const int l0 = ch * LCH;
    const float* hb = h1 + (size_t)b * NLM * OUT_C;

    for (int i = threadIdx.x; i < 2 * OUT_C; i += 256) (&red[0][0])[i] = 0.f;

    for (int i = threadIdx.x; i < (LCH + 2) * 32; i += 256) {
        int t  = i >> 5;
        int c4 = (i & 31) << 2;
        int l  = l0 - 1 + t;
        float4 v = make_float4(0.f, 0.f, 0.f, 0.f);
        if (l >= 0 && l < NLM) {
            v = *reinterpret_cast<const float4*>(hb + (size_t)l * OUT_C + c4);
            v.x = fmaxf(0.f, v.x * sc[c4 + 0] + sh[c4 + 0]);
            v.y = fmaxf(0.f, v.y * sc[c4 + 1] + sh[c4 + 1]);
            v.z = fmaxf(0.f, v.z * sc[c4 + 2] + sh[c4 + 2]);
            v.w = fmaxf(0.f, v.w * sc[c4 + 3] + sh[c4 + 3]);
        }
        ushort4 u;
        u.x = f2bf(v.x); u.y = f2bf(v.y); u.z = f2bf(v.z); u.w = f2bf(v.w);
        int byte = t * 256 + ((((c4 >> 3) ^ (t & 7)) & 15) << 4) + ((c4 & 7) << 1);
        *reinterpret_cast<ushort4*>(reinterpret_cast<char*>(tile) + byte) = u;
    }
    __syncthreads();

    const int w    = threadIdx.x >> 6;    // wave 0..3 -> out cols [32w, 32w+32)
    const int lane = threadIdx.x & 63;
    const int r16  = lane & 15;
    const int kg   = lane >> 4;           // 0..3

    f32x4 acc[4][2];
    #pragma unroll
    for (int rs = 0; rs < 4; ++rs)
        #pragma unroll
        for (int cs = 0; cs < 2; ++cs)
            acc[rs][cs] = (f32x4){0.f, 0.f, 0.f, 0.f};

    for (int ks = 0; ks < 12; ++ks) {
        const int ktap = ks >> 2;
        const int slotbase = (ks & 3) * 4 + kg;
        bf16x8 bfr[2];
        #pragma unroll
        for (int cs = 0; cs < 2; ++cs) {
            const int g = w * 2 + cs;
            uint4 u = *reinterpret_cast<const uint4*>(wBf + (((ks * 8 + g) * 64 + lane) << 3));
            bfr[cs] = __builtin_bit_cast(bf16x8, u);
        }
        #pragma unroll
        for (int rs = 0; rs < 4; ++rs) {
            const int t = rs * 16 + r16 + ktap;
            const int byte = t * 256 + (((slotbase ^ (t & 7)) & 15) << 4);
            uint4 u = *reinterpret_cast<const uint4*>(reinterpret_cast<const char*>(tile) + byte);
            bf16x8 af = __builtin_bit_cast(bf16x8, u);
            acc[rs][0] = __builtin_amdgcn_mfma_f32_16x16x32_bf16(af, bfr[0], acc[rs][0], 0, 0, 0);
            acc[rs][1] = __builtin_amdgcn_mfma_f32_16x16x32_bf16(af, bfr[1], acc[rs][1], 0, 0, 0);
        }
    }

    #pragma unroll
    for (int cs = 0; cs < 2; ++cs) {
        const int col = w * 32 + cs * 16 + r16;
        const float bias = cb[col];
        float s = 0.f, q = 0.f;
        #pragma unroll
        for (int rs = 0; rs < 4; ++rs) {
            #pragma unroll
            for (int reg = 0; reg < 4; ++reg) {
                int l = l0 + rs * 16 + kg * 4 + reg;
                if (l < NLM) {
                    float v = acc[rs][cs][reg] + bias;
                    out[((size_t)b * NLM + l) * OUT_C + col] = v;
                    s += v;
                    q += v * v;
                }
            }
        }
        atomicAdd(&red[0][col], s);
        atomicAdd(&red[1][col], q);
    }
    __syncthreads();
    if (threadIdx.x < OUT_C) {
        atomicAdd(&sums[threadIdx.x], red[0][threadIdx.x]);
        atomicAdd(&sums[OUT_C + threadIdx.x], red[1][threadIdx.x]);
    }
}

// ---- BN2+ReLU + residual (x @ rwT) + add, register-blocked 8x8, in place ----
__global__ __launch_bounds__(128) void k_final(float* __restrict__ out,
                                               const float* __restrict__ x,
                                               const float* __restrict__ rwT,
                                               const float* __restrict__ rb,
                                               const float* __restrict__ sc,
                                               const float* __restrict__ sh) {
    __shared__ float4 X[GN][16];       // x tile, slot-swizzled
    const int n0 = blockIdx.x * GN;

    for (int i = threadIdx.x; i < GN * 16; i += 128) {
        int n = i >> 4, s = i & 15;
        int ss = s ^ (n >> 3);
        X[n][ss] = *reinterpret_cast<const float4*>(x + (size_t)(n0 + n) * IN_C + s * 4);
    }
    __syncthreads();

    const int oq = threadIdx.x & 15;
    const int nr = threadIdx.x >> 4;
    const int o0 = oq * 8;

    float acc[8][8];
    {
        float4 b0 = *reinterpret_cast<const float4*>(rb + o0);
        float4 b1 = *reinterpret_cast<const float4*>(rb + o0 + 4);
        #pragma unroll
        for (int j = 0; j < 8; ++j) {
            acc[j][0] = b0.x; acc[j][1] = b0.y; acc[j][2] = b0.z; acc[j][3] = b0.w;
            acc[j][4] = b1.x; acc[j][5] = b1.y; acc[j][6] = b1.z; acc[j][7] = b1.w;
        }
    }

    for (int s = 0; s < 16; ++s) {
        const int ss = s ^ nr;
        float4 x4[8];
        #pragma unroll
        for (int j = 0; j < 8; ++j) x4[j] = X[nr * 8 + j][ss];
        #pragma unroll
        for (int c = 0; c < 4; ++c) {
            const int k = s * 4 + c;
            float4 w0 = *reinterpret_cast<const float4*>(rwT + (size_t)k * OUT_C + o0);
            float4 w1 = *reinterpret_cast<const float4*>(rwT + (size_t)k * OUT_C + o0 + 4);
            #pragma unroll
            for (int j = 0; j < 8; ++j) {
                const float xv = (&x4[j].x)[c];
                acc[j][0] += xv * w0.x;
                acc[j][1] += xv * w0.y;
                acc[j][2] += xv * w0.z;
                acc[j][3] += xv * w0.w;
                acc[j][4] += xv * w1.x;
                acc[j][5] += xv * w1.y;
                acc[j][6] += xv * w1.z;
                acc[j][7] += xv * w1.w;
            }
        }
    }

    float4 s0 = *reinterpret_cast<const float4*>(sc + o0);
    float4 s1 = *reinterpret_cast<const float4*>(sc + o0 + 4);
    float4 h0 = *reinterpret_cast<const float4*>(sh + o0);
    float4 h1 = *reinterpret_cast<const float4*>(sh + o0 + 4);
    #pragma unroll
    for (int j = 0; j < 8; ++j) {
        float* op = out + (size_t)(n0 + nr * 8 + j) * OUT_C + o0;
        float4 v0 = *reinterpret_cast<float4*>(op);
        float4 v1 = *reinterpret_cast<float4*>(op + 4);
        v0.x = fmaxf(0.f, v0.x * s0.x + h0.x) + acc[j][0];
        v0.y = fmaxf(0.f, v0.y * s0.y + h0.y) + acc[j][1];
        v0.z = fmaxf(0.f, v0.z * s0.z + h0.z) + acc[j][2];
        v0.w = fmaxf(0.f, v0.w * s0.w + h0.w) + acc[j][3];
        v1.x = fmaxf(0.f, v1.x * s1.x + h1.x) + acc[j][4];
        v1.y = fmaxf(0.f, v1.y * s1.y + h1.y) + acc[j][5];
        v1.z = fmaxf(0.f, v1.z * s1.z + h1.z) + acc[j][6];
        v1.w = fmaxf(0.f, v1.w * s1.w + h1.w) + acc[j][7];
        *reinterpret_cast<float4*>(op)     = v0;
        *reinterpret_cast<float4*>(op + 4) = v1;
    }
}

extern "C" void kernel_launch(void* const* d_in, const int* in_sizes, int n_in,
                              void* d_out, int out_size, void* d_ws, size_t ws_size,
                              hipStream_t stream) {
    const float* x     = (const float*)d_in[0];
    const int*   ei    = (const int*)d_in[1];
    const float* Wrel  = (const float*)d_in[3];
    const float* brel  = (const float*)d_in[4];
    const float* Wroot = (const float*)d_in[5];
    const float* bn1g  = (const float*)d_in[6];
    const float* bn1b  = (const float*)d_in[7];
    const float* convw = (const float*)d_in[8];
    const float* convb = (const float*)d_in[9];
    const float* bn2g  = (const float*)d_in[10];
    const float* bn2b  = (const float*)d_in[11];
    const float* resw  = (const float*)d_in[12];
    const float* resb  = (const float*)d_in[13];
    float* out = (float*)d_out;

    float* agg = (float*)d_ws;                                // N*64 f32 (61.3 MB)
    float* h   = agg + (size_t)N_NODES * IN_C;                // N*128 f32 (122.7 MB)
    float* st  = h + (size_t)N_NODES * OUT_C;                 // small tail
    float* sums1 = st;        float* sc1 = st + 256; float* sh1 = st + 384;
    float* sums2 = st + 512;  float* sc2 = st + 768; float* sh2 = st + 896;
    float* rwT = st + 1024;                                   // 8192 f32
    unsigned short* wBf = (unsigned short*)(st + 1024 + 8192);// 49152 bf16 (96 KB)
    unsigned short* wG  = wBf + 49152;                        // 16384 bf16 (32 KB)

    // CSR arrays live inside h's memory: h is only written AFTER the gather.
    int* hist  = (int*)h;
    int* off   = hist + N_NODES;
    int* cur   = off + N_NODES;
    int* btot  = cur + N_NODES;
    int* elist = btot + 256;          // E ints; total 18.2 MB << 122.7 MB

    hipMemsetAsync(hist, 0, (size_t)N_NODES * sizeof(int), stream);
    hipMemsetAsync(st, 0, 1024 * sizeof(float), stream);

    k_trw   <<<32, 256, 0, stream>>>(resw, rwT);
    k_wprep <<<192, 256, 0, stream>>>(convw, wBf);
    k_wprep2<<<64, 256, 0, stream>>>(Wrel, Wroot, wG);
    k_hist  <<<NEDGE / 256, 256, 0, stream>>>(ei, hist);
    k_scan1 <<<N_NODES / 1024, 256, 0, stream>>>(hist, off, btot);
    k_scan2 <<<1, 256, 0, stream>>>(btot);
    k_scan3 <<<N_NODES / 256, 256, 0, stream>>>(off, btot, cur);
    k_fill  <<<FILLB, 256, 0, stream>>>(ei, cur, elist);
    k_gather<<<(N_NODES * 16) / 256, 256, 0, stream>>>(x, off, hist, elist, agg);

    k_gemm1<<<N_NODES / GM, 256, 0, stream>>>(agg, x, wG, brel, h, sums1);
    k_bnparams<<<1, 128, 0, stream>>>(sums1, bn1g, bn1b, sc1, sh1);
    k_conv<<<BSZ * NCH, 256, 0, stream>>>(h, wBf, convb, sc1, sh1, out, sums2);
    k_bnparams<<<1, 128, 0, stream>>>(sums2, bn2g, bn2b, sc2, sh2);
    k_final<<<N_NODES / GN, 128, 0, stream>>>(out, x, rwT, resb, sc2, sh2);
}

// Round 10
// 745.855 us; speedup vs baseline: 1.1321x; 1.1321x over previous
//
#include <hip/hip_runtime.h>

#define N_NODES 239616
#define NLM 468
#define BSZ 512
#define NEDGE 3833856
#define IN_C 64
#define OUT_C 128
#define KW 3
#define EPSV 1e-5f

#define GM 128      // nodes per gemm1 block (MFMA tile M)
#define GN 64       // nodes per final block
#define LCH 64      // L-rows per conv block
#define NCH 8       // ceil(468/64)
#define NPASS 8     // XCD count; dst-range classes in k_fill
#define FILLB 2048  // k_fill grid (fully resident -> bid%8 == XCD holds)

typedef __attribute__((ext_vector_type(8))) __bf16 bf16x8;
typedef __attribute__((ext_vector_type(4))) float f32x4;

__device__ inline unsigned short f2bf(float f) {
    unsigned int u = __builtin_bit_cast(unsigned int, f);
    u = (u + 0x7FFFu + ((u >> 16) & 1u)) >> 16;
    return (unsigned short)u;
}

// ================= CSR build (counting sort by dst) =================

__global__ __launch_bounds__(256) void k_hist(const int* __restrict__ ei,
                                              int* __restrict__ hist) {
    int i = blockIdx.x * 256 + threadIdx.x;   // E/4 threads
    int4 d4 = reinterpret_cast<const int4*>(ei + NEDGE)[i];
    atomicAdd(&hist[d4.x], 1);
    atomicAdd(&hist[d4.y], 1);
    atomicAdd(&hist[d4.z], 1);
    atomicAdd(&hist[d4.w], 1);
}

__global__ __launch_bounds__(256) void k_scan1(const int* __restrict__ hist,
                                               int* __restrict__ off,
                                               int* __restrict__ btot) {
    __shared__ int ts[256];
    int base = blockIdx.x * 1024 + threadIdx.x * 4;
    int4 v = *reinterpret_cast<const int4*>(hist + base);
    int s = v.x + v.y + v.z + v.w;
    ts[threadIdx.x] = s;
    __syncthreads();
    for (int d = 1; d < 256; d <<= 1) {
        int t = (threadIdx.x >= d) ? ts[threadIdx.x - d] : 0;
        __syncthreads();
        ts[threadIdx.x] += t;
        __syncthreads();
    }
    int excl = ts[threadIdx.x] - s;
    int4 o;
    o.x = excl; o.y = excl + v.x; o.z = o.y + v.y; o.w = o.z + v.z;
    *reinterpret_cast<int4*>(off + base) = o;
    if (threadIdx.x == 255) btot[blockIdx.x] = ts[255];
}

__global__ void k_scan2(int* __restrict__ btot) {
    __shared__ int ts[256];
    int v = (threadIdx.x < (N_NODES / 1024)) ? btot[threadIdx.x] : 0;
    ts[threadIdx.x] = v;
    __syncthreads();
    for (int d = 1; d < 256; d <<= 1) {
        int t = (threadIdx.x >= d) ? ts[threadIdx.x - d] : 0;
        __syncthreads();
        ts[threadIdx.x] += t;
        __syncthreads();
    }
    if (threadIdx.x < (N_NODES / 1024)) btot[threadIdx.x] = ts[threadIdx.x] - v;
}

__global__ __launch_bounds__(256) void k_scan3(int* __restrict__ off,
                                               const int* __restrict__ btot,
                                               int* __restrict__ cur) {
    int i = blockIdx.x * 256 + threadIdx.x;   // N threads
    int v = off[i] + btot[i >> 10];
    off[i] = v;
    cur[i] = v;
}

// XCD-ranged fill: blocks with bid%8==p handle dst in [p*N/8,(p+1)*N/8).
__global__ __launch_bounds__(256) void k_fill(const int* __restrict__ ei,
                                              int* __restrict__ cur,
                                              int* __restrict__ elist) {
    const int pass = blockIdx.x & 7;
    const int lo = pass * (N_NODES / NPASS);
    const int hi = lo + (N_NODES / NPASS);
    const int tid = (blockIdx.x >> 3) * 256 + threadIdx.x;   // 0..65535
    const int stride = (FILLB / NPASS) * 256;                // 65536
    const int E4 = NEDGE / 4;
    for (int i = tid; i < E4; i += stride) {
        int4 d4 = reinterpret_cast<const int4*>(ei + NEDGE)[i];
        bool m0 = (d4.x >= lo && d4.x < hi);
        bool m1 = (d4.y >= lo && d4.y < hi);
        bool m2 = (d4.z >= lo && d4.z < hi);
        bool m3 = (d4.w >= lo && d4.w < hi);
        if (!(m0 | m1 | m2 | m3)) continue;
        int4 s4 = reinterpret_cast<const int4*>(ei)[i];
        if (m0) elist[atomicAdd(&cur[d4.x], 1)] = s4.x;
        if (m1) elist[atomicAdd(&cur[d4.y], 1)] = s4.y;
        if (m2) elist[atomicAdd(&cur[d4.z], 1)] = s4.z;
        if (m3) elist[atomicAdd(&cur[d4.w], 1)] = s4.w;
    }
}

// ---------------- x (f32) -> xb (bf16) ----------------
__global__ __launch_bounds__(256) void k_xprep(const float* __restrict__ x,
                                               unsigned short* __restrict__ xb) {
    int i = blockIdx.x * 256 + threadIdx.x;   // N*64/8 threads
    float4 f0 = *reinterpret_cast<const float4*>(x + (size_t)i * 8);
    float4 f1 = *reinterpret_cast<const float4*>(x + (size_t)i * 8 + 4);
    uint4 u;
    u.x = f2bf(f0.x) | ((unsigned)f2bf(f0.y) << 16);
    u.y = f2bf(f0.z) | ((unsigned)f2bf(f0.w) << 16);
    u.z = f2bf(f1.x) | ((unsigned)f2bf(f1.y) << 16);
    u.w = f2bf(f1.z) | ((unsigned)f2bf(f1.w) << 16);
    *reinterpret_cast<uint4*>(xb + (size_t)i * 8) = u;
}

// agg[n] = sum of bf16 x rows over in-edges; 8 lanes/node, f32 accum, bf16 out
__global__ __launch_bounds__(256) void k_gather(const unsigned short* __restrict__ xb,
                                                const int* __restrict__ off,
                                                const int* __restrict__ hist,
                                                const int* __restrict__ elist,
                                                unsigned short* __restrict__ aggb) {
    int t = blockIdx.x * 256 + threadIdx.x;   // N*8 threads
    int n = t >> 3;
    int j = (t & 7) * 8;                      // channel base
    int start = off[n];
    int deg   = hist[n];
    float a[8];
    #pragma unroll
    for (int c = 0; c < 8; ++c) a[c] = 0.f;
    for (int i = 0; i < deg; ++i) {
        int s = elist[start + i];
        uint4 u = *reinterpret_cast<const uint4*>(xb + (size_t)s * IN_C + j);
        unsigned w[4] = {u.x, u.y, u.z, u.w};
        #pragma unroll
        for (int c = 0; c < 4; ++c) {
            a[2 * c]     += __builtin_bit_cast(float, w[c] << 16);
            a[2 * c + 1] += __builtin_bit_cast(float, w[c] & 0xffff0000u);
        }
    }
    uint4 o;
    o.x = f2bf(a[0]) | ((unsigned)f2bf(a[1]) << 16);
    o.y = f2bf(a[2]) | ((unsigned)f2bf(a[3]) << 16);
    o.z = f2bf(a[4]) | ((unsigned)f2bf(a[5]) << 16);
    o.w = f2bf(a[6]) | ((unsigned)f2bf(a[7]) << 16);
    *reinterpret_cast<uint4*>(aggb + (size_t)n * IN_C + j) = o;
}

// --- pack Wcat = [W_rel; W_root] (128x128, k-major) -> bf16 B-fragments [4][8][64][8] ---
__global__ __launch_bounds__(256) void k_wprep2(const float* __restrict__ Wrel,
                                                const float* __restrict__ Wroot,
                                                unsigned short* __restrict__ wG) {
    int i = blockIdx.x * 256 + threadIdx.x;   // 16384 threads
    int j    = i & 7;
    int lane = (i >> 3) & 63;
    int g    = (i >> 9) & 7;
    int ks   = i >> 12;
    int o    = g * 16 + (lane & 15);
    int k    = ks * 32 + ((lane >> 4) << 3) + j;
    float v = (k < IN_C) ? Wrel[k * OUT_C + o] : Wroot[(k - IN_C) * OUT_C + o];
    wG[i] = f2bf(v);
}

// ======== h = [agg||x] @ Wcat + b_rel via bf16 MFMA, fused BN1 stats ========
__global__ __launch_bounds__(256) void k_gemm1(const unsigned short* __restrict__ aggb,
                                               const unsigned short* __restrict__ xb,
                                               const unsigned short* __restrict__ wG,
                                               const float* __restrict__ brel,
                                               float* __restrict__ h,
                                               float* __restrict__ sums) {
    __shared__ unsigned short tile[GM * 128];   // bf16 A-tile, XOR-swizzled, 32 KB
    __shared__ float red[2][OUT_C];
    const int n0 = blockIdx.x * GM;

    for (int i = threadIdx.x; i < 2 * OUT_C; i += 256) (&red[0][0])[i] = 0.f;

    // stage [aggb(64) || xb(64)] per node, straight uint4 copies + XOR swizzle
    for (int i = threadIdx.x; i < GM * 16; i += 256) {
        int t = i >> 4, s = i & 15;
        const unsigned short* src = (s < 8) ? (aggb + (size_t)(n0 + t) * IN_C + s * 8)
                                            : (xb   + (size_t)(n0 + t) * IN_C + (s - 8) * 8);
        uint4 u = *reinterpret_cast<const uint4*>(src);
        int byte = t * 256 + (((s ^ (t & 7)) & 15) << 4);
        *reinterpret_cast<uint4*>(reinterpret_cast<char*>(tile) + byte) = u;
    }
    __syncthreads();

    const int w    = threadIdx.x >> 6;    // wave -> rows [32w, 32w+32)
    const int lane = threadIdx.x & 63;
    const int r16  = lane & 15;
    const int kg   = lane >> 4;           // 0..3

    f32x4 acc[2][8];
    #pragma unroll
    for (int rs = 0; rs < 2; ++rs)
        #pragma unroll
        for (int g = 0; g < 8; ++g)
            acc[rs][g] = (f32x4){0.f, 0.f, 0.f, 0.f};

    for (int ks = 0; ks < 4; ++ks) {
        bf16x8 a[2];
        #pragma unroll
        for (int rs = 0; rs < 2; ++rs) {
            const int t = w * 32 + rs * 16 + r16;
            const int slot = ks * 4 + kg;
            const int byte = t * 256 + (((slot ^ (t & 7)) & 15) << 4);
            uint4 u = *reinterpret_cast<const uint4*>(reinterpret_cast<const char*>(tile) + byte);
            a[rs] = __builtin_bit_cast(bf16x8, u);
        }
        #pragma unroll
        for (int g = 0; g < 8; ++g) {
            uint4 u = *reinterpret_cast<const uint4*>(wG + (((ks * 8 + g) * 64 + lane) << 3));
            bf16x8 b = __builtin_bit_cast(bf16x8, u);
            acc[0][g] = __builtin_amdgcn_mfma_f32_16x16x32_bf16(a[0], b, acc[0][g], 0, 0, 0);
            acc[1][g] = __builtin_amdgcn_mfma_f32_16x16x32_bf16(a[1], b, acc[1][g], 0, 0, 0);
        }
    }

    #pragma unroll
    for (int g = 0; g < 8; ++g) {
        const int col = g * 16 + r16;
        const float bias = brel[col];
        float s = 0.f, q = 0.f;
        #pragma unroll
        for (int rs = 0; rs < 2; ++rs) {
            #pragma unroll
            for (int reg = 0; reg < 4; ++reg) {
                const int row = n0 + w * 32 + rs * 16 + kg * 4 + reg;
                float v = acc[rs][g][reg] + bias;
                h[(size_t)row * OUT_C + col] = v;
                s += v;
                q += v * v;
            }
        }
        atomicAdd(&red[0][col], s);
        atomicAdd(&red[1][col], q);
    }
    __syncthreads();
    if (threadIdx.x < OUT_C) {
        atomicAdd(&sums[threadIdx.x], red[0][threadIdx.x]);
        atomicAdd(&sums[OUT_C + threadIdx.x], red[1][threadIdx.x]);
    }
}

// ---------------- BN scale/shift from sums ----------------
__global__ void k_bnparams(const float* __restrict__ sums,
                           const float* __restrict__ g,
                           const float* __restrict__ b,
                           float* __restrict__ sc, float* __restrict__ sh) {
    int c = threadIdx.x;   // 128 threads
    const float inv_n = 1.0f / (float)N_NODES;
    float mean = sums[c] * inv_n;
    float var  = sums[OUT_C + c] * inv_n - mean * mean;
    float s = g[c] * rsqrtf(var + EPSV);
    sc[c] = s;
    sh[c] = b[c] - mean * s;
}

// ---------------- transpose res_w [128][64] -> rwT [64][128] ----------------
__global__ __launch_bounds__(256) void k_trw(const float* __restrict__ rw,
                                             float* __restrict__ rwT) {
    int i = blockIdx.x * 256 + threadIdx.x;   // 8192 threads
    int o = i >> 6;
    int k = i & 63;
    rwT[k * OUT_C + o] = rw[i];
}

// ----- pack conv_w [O][CI][KW] f32 -> bf16 B-fragments [12][8][64][8] -----
__global__ __launch_bounds__(256) void k_wprep(const float* __restrict__ w,
                                               unsigned short* __restrict__ wBf) {
    int i = blockIdx.x * 256 + threadIdx.x;   // 49152 threads
    int j    = i & 7;
    int lane = (i >> 3) & 63;
    int g    = (i >> 9) & 7;
    int ks   = i >> 12;
    int o    = g * 16 + (lane & 15);
    int ci   = (ks & 3) * 32 + ((lane >> 4) << 3) + j;
    int ktap = ks >> 2;
    wBf[i] = f2bf(w[o * (OUT_C * KW) + ci * KW + ktap]);
}

// ------- Conv1d via bf16 MFMA: BN1+ReLU fused at staging, BN2 stats fused -------
__global__ __launch_bounds__(256) void k_conv(const float* __restrict__ h1,
                                              const unsigned short* __restrict__ wBf,
                                              const float* __restrict__ cb,
                                              const float* __restrict__ sc,
                                              const float* __restrict__ sh,
                                              float* __restrict__ out,
                                              float* __restrict__ sums) {
    __shared__ unsigned short tile[(LCH + 2) * OUT_C];   // bf16, XOR-swizzled, 16.9 KB
    __shared__ float red[2][OUT_C];
    const int b  = blockIdx.x >> 3;
    const int ch = blockIdx.x & 7;
    const int l0 = ch * LCH;
    const float* hb = h1 + (size_t)b * NLM * OUT_C;

    for (int i = threadIdx.x; i < 2 * OUT_C; i += 256) (&red[0][0])[i] = 0.f;

    for (int i = threadIdx.x; i < (LCH + 2) * 32; i += 256) {
        int t  = i >> 5;
        int c4 = (i & 31) << 2;
        int l  = l0 - 1 + t;
        float4 v = make_float4(0.f, 0.f, 0.f, 0.f);
        if (l >= 0 && l < NLM) {
            v = *reinterpret_cast<const float4*>(hb + (size_t)l * OUT_C + c4);
            v.x = fmaxf(0.f, v.x * sc[c4 + 0] + sh[c4 + 0]);
            v.y = fmaxf(0.f, v.y * sc[c4 + 1] + sh[c4 + 1]);
            v.z = fmaxf(0.f, v.z * sc[c4 + 2] + sh[c4 + 2]);
            v.w = fmaxf(0.f, v.w * sc[c4 + 3] + sh[c4 + 3]);
        }
        ushort4 u;
        u.x = f2bf(v.x); u.y = f2bf(v.y); u.z = f2bf(v.z); u.w = f2bf(v.w);
        int byte = t * 256 + ((((c4 >> 3) ^ (t & 7)) & 15) << 4) + ((c4 & 7) << 1);
        *reinterpret_cast<ushort4*>(reinterpret_cast<char*>(tile) + byte) = u;
    }
    __syncthreads();

    const int w    = threadIdx.x >> 6;    // wave 0..3 -> out cols [32w, 32w+32)
    const int lane = threadIdx.x & 63;
    const int r16  = lane & 15;
    const int kg   = lane >> 4;           // 0..3

    f32x4 acc[4][2];
    #pragma unroll
    for (int rs = 0; rs < 4; ++rs)
        #pragma unroll
        for (int cs = 0; cs < 2; ++cs)
            acc[rs][cs] = (f32x4){0.f, 0.f, 0.f, 0.f};

    for (int ks = 0; ks < 12; ++ks) {
        const int ktap = ks >> 2;
        const int slotbase = (ks & 3) * 4 + kg;
        bf16x8 bfr[2];
        #pragma unroll
        for (int cs = 0; cs < 2; ++cs) {
            const int g = w * 2 + cs;
            uint4 u = *reinterpret_cast<const uint4*>(wBf + (((ks * 8 + g) * 64 + lane) << 3));
            bfr[cs] = __builtin_bit_cast(bf16x8, u);
        }
        #pragma unroll
        for (int rs = 0; rs < 4; ++rs) {
            const int t = rs * 16 + r16 + ktap;
            const int byte = t * 256 + (((slotbase ^ (t & 7)) & 15) << 4);
            uint4 u = *reinterpret_cast<const uint4*>(reinterpret_cast<const char*>(tile) + byte);
            bf16x8 af = __builtin_bit_cast(bf16x8, u);
            acc[rs][0] = __builtin_amdgcn_mfma_f32_16x16x32_bf16(af, bfr[0], acc[rs][0], 0, 0, 0);
            acc[rs][1] = __builtin_amdgcn_mfma_f32_16x16x32_bf16(af, bfr[1], acc[rs][1], 0, 0, 0);
        }
    }

    #pragma unroll
    for (int cs = 0; cs < 2; ++cs) {
        const int col = w * 32 + cs * 16 + r16;
        const float bias = cb[col];
        float s = 0.f, q = 0.f;
        #pragma unroll
        for (int rs = 0; rs < 4; ++rs) {
            #pragma unroll
            for (int reg = 0; reg < 4; ++reg) {
                int l = l0 + rs * 16 + kg * 4 + reg;
                if (l < NLM) {
                    float v = acc[rs][cs][reg] + bias;
                    out[((size_t)b * NLM + l) * OUT_C + col] = v;
                    s += v;
                    q += v * v;
                }
            }
        }
        atomicAdd(&red[0][col], s);
        atomicAdd(&red[1][col], q);
    }
    __syncthreads();
    if (threadIdx.x < OUT_C) {
        atomicAdd(&sums[threadIdx.x], red[0][threadIdx.x]);
        atomicAdd(&sums[OUT_C + threadIdx.x], red[1][threadIdx.x]);
    }
}

// ---- BN2+ReLU + residual (x @ rwT) + add, register-blocked 8x8, in place ----
__global__ __launch_bounds__(128) void k_final(float* __restrict__ out,
                                               const float* __restrict__ x,
                                               const float* __restrict__ rwT,
                                               const float* __restrict__ rb,
                                               const float* __restrict__ sc,
                                               const float* __restrict__ sh) {
    __shared__ float4 X[GN][16];       // x tile, slot-swizzled
    const int n0 = blockIdx.x * GN;

    for (int i = threadIdx.x; i < GN * 16; i += 128) {
        int n = i >> 4, s = i & 15;
        int ss = s ^ (n >> 3);
        X[n][ss] = *reinterpret_cast<const float4*>(x + (size_t)(n0 + n) * IN_C + s * 4);
    }
    __syncthreads();

    const int oq = threadIdx.x & 15;
    const int nr = threadIdx.x >> 4;
    const int o0 = oq * 8;

    float acc[8][8];
    {
        float4 b0 = *reinterpret_cast<const float4*>(rb + o0);
        float4 b1 = *reinterpret_cast<const float4*>(rb + o0 + 4);
        #pragma unroll
        for (int j = 0; j < 8; ++j) {
            acc[j][0] = b0.x; acc[j][1] = b0.y; acc[j][2] = b0.z; acc[j][3] = b0.w;
            acc[j][4] = b1.x; acc[j][5] = b1.y; acc[j][6] = b1.z; acc[j][7] = b1.w;
        }
    }

    for (int s = 0; s < 16; ++s) {
        const int ss = s ^ nr;
        float4 x4[8];
        #pragma unroll
        for (int j = 0; j < 8; ++j) x4[j] = X[nr * 8 + j][ss];
        #pragma unroll
        for (int c = 0; c < 4; ++c) {
            const int k = s * 4 + c;
            float4 w0 = *reinterpret_cast<const float4*>(rwT + (size_t)k * OUT_C + o0);
            float4 w1 = *reinterpret_cast<const float4*>(rwT + (size_t)k * OUT_C + o0 + 4);
            #pragma unroll
            for (int j = 0; j < 8; ++j) {
                const float xv = (&x4[j].x)[c];
                acc[j][0] += xv * w0.x;
                acc[j][1] += xv * w0.y;
                acc[j][2] += xv * w0.z;
                acc[j][3] += xv * w0.w;
                acc[j][4] += xv * w1.x;
                acc[j][5] += xv * w1.y;
                acc[j][6] += xv * w1.z;
                acc[j][7] += xv * w1.w;
            }
        }
    }

    float4 s0 = *reinterpret_cast<const float4*>(sc + o0);
    float4 s1 = *reinterpret_cast<const float4*>(sc + o0 + 4);
    float4 h0 = *reinterpret_cast<const float4*>(sh + o0);
    float4 h1 = *reinterpret_cast<const float4*>(sh + o0 + 4);
    #pragma unroll
    for (int j = 0; j < 8; ++j) {
        float* op = out + (size_t)(n0 + nr * 8 + j) * OUT_C + o0;
        float4 v0 = *reinterpret_cast<float4*>(op);
        float4 v1 = *reinterpret_cast<float4*>(op + 4);
        v0.x = fmaxf(0.f, v0.x * s0.x + h0.x) + acc[j][0];
        v0.y = fmaxf(0.f, v0.y * s0.y + h0.y) + acc[j][1];
        v0.z = fmaxf(0.f, v0.z * s0.z + h0.z) + acc[j][2];
        v0.w = fmaxf(0.f, v0.w * s0.w + h0.w) + acc[j][3];
        v1.x = fmaxf(0.f, v1.x * s1.x + h1.x) + acc[j][4];
        v1.y = fmaxf(0.f, v1.y * s1.y + h1.y) + acc[j][5];
        v1.z = fmaxf(0.f, v1.z * s1.z + h1.z) + acc[j][6];
        v1.w = fmaxf(0.f, v1.w * s1.w + h1.w) + acc[j][7];
        *reinterpret_cast<float4*>(op)     = v0;
        *reinterpret_cast<float4*>(op + 4) = v1;
    }
}

extern "C" void kernel_launch(void* const* d_in, const int* in_sizes, int n_in,
                              void* d_out, int out_size, void* d_ws, size_t ws_size,
                              hipStream_t stream) {
    const float* x     = (const float*)d_in[0];
    const int*   ei    = (const int*)d_in[1];
    const float* Wrel  = (const float*)d_in[3];
    const float* brel  = (const float*)d_in[4];
    const float* Wroot = (const float*)d_in[5];
    const float* bn1g  = (const float*)d_in[6];
    const float* bn1b  = (const float*)d_in[7];
    const float* convw = (const float*)d_in[8];
    const float* convb = (const float*)d_in[9];
    const float* bn2g  = (const float*)d_in[10];
    const float* bn2b  = (const float*)d_in[11];
    const float* resw  = (const float*)d_in[12];
    const float* resb  = (const float*)d_in[13];
    float* out = (float*)d_out;

    unsigned short* aggb = (unsigned short*)d_ws;             // N*64 bf16 (30.7 MB)
    unsigned short* xb   = aggb + (size_t)N_NODES * IN_C;     // N*64 bf16 (30.7 MB)
    float* h   = (float*)(xb + (size_t)N_NODES * IN_C);       // N*128 f32 (122.7 MB)
    float* st  = h + (size_t)N_NODES * OUT_C;                 // small tail
    float* sums1 = st;        float* sc1 = st + 256; float* sh1 = st + 384;
    float* sums2 = st + 512;  float* sc2 = st + 768; float* sh2 = st + 896;
    float* rwT = st + 1024;                                   // 8192 f32
    unsigned short* wBf = (unsigned short*)(st + 1024 + 8192);// 49152 bf16 (96 KB)
    unsigned short* wG  = wBf + 49152;                        // 16384 bf16 (32 KB)

    // CSR arrays live inside h's memory: h is only written AFTER the gather.
    int* hist  = (int*)h;
    int* off   = hist + N_NODES;
    int* cur   = off + N_NODES;
    int* btot  = cur + N_NODES;
    int* elist = btot + 256;          // E ints; total 18.2 MB << 122.7 MB

    hipMemsetAsync(hist, 0, (size_t)N_NODES * sizeof(int), stream);
    hipMemsetAsync(st, 0, 1024 * sizeof(float), stream);

    k_xprep <<<N_NODES / 32, 256, 0, stream>>>(x, xb);
    k_trw   <<<32, 256, 0, stream>>>(resw, rwT);
    k_wprep <<<192, 256, 0, stream>>>(convw, wBf);
    k_wprep2<<<64, 256, 0, stream>>>(Wrel, Wroot, wG);
    k_hist  <<<NEDGE / 1024, 256, 0, stream>>>(ei, hist);
    k_scan1 <<<N_NODES / 1024, 256, 0, stream>>>(hist, off, btot);
    k_scan2 <<<1, 256, 0, stream>>>(btot);
    k_scan3 <<<N_NODES / 256, 256, 0, stream>>>(off, btot, cur);
    k_fill  <<<FILLB, 256, 0, stream>>>(ei, cur, elist);
    k_gather<<<(N_NODES * 8) / 256, 256, 0, stream>>>(xb, off, hist, elist, aggb);

    k_gemm1<<<N_NODES / GM, 256, 0, stream>>>(aggb, xb, wG, brel, h, sums1);
    k_bnparams<<<1, 128, 0, stream>>>(sums1, bn1g, bn1b, sc1, sh1);
    k_conv<<<BSZ * NCH, 256, 0, stream>>>(h, wBf, convb, sc1, sh1, out, sums2);
    k_bnparams<<<1, 128, 0, stream>>>(sums2, bn2g, bn2b, sc2, sh2);
    k_final<<<N_NODES / GN, 128, 0, stream>>>(out, x, rwT, resb, sc2, sh2);
}

// Round 11
// 696.884 us; speedup vs baseline: 1.2117x; 1.0703x over previous
//
#include <hip/hip_runtime.h>

#define N_NODES 239616
#define NLM 468
#define BSZ 512
#define NEDGE 3833856
#define IN_C 64
#define OUT_C 128
#define KW 3
#define EPSV 1e-5f

#define GM 128      // nodes per gemm1/final block (MFMA tile M)
#define LCH 64      // L-rows per conv block
#define NCH 8       // ceil(468/64)
#define NPASS 8     // XCD count; dst-range classes in k_fill
#define FILLB 2048  // k_fill grid (fully resident -> bid%8 == XCD holds)

typedef __attribute__((ext_vector_type(8))) __bf16 bf16x8;
typedef __attribute__((ext_vector_type(4))) float f32x4;

__device__ inline unsigned short f2bf(float f) {
    unsigned int u = __builtin_bit_cast(unsigned int, f);
    u = (u + 0x7FFFu + ((u >> 16) & 1u)) >> 16;
    return (unsigned short)u;
}
__device__ inline float bf2f(unsigned short b) {
    return __builtin_bit_cast(float, (unsigned)b << 16);
}

// ================= CSR build (counting sort by dst) =================

__global__ __launch_bounds__(256) void k_hist(const int* __restrict__ ei,
                                              int* __restrict__ hist) {
    int i = blockIdx.x * 256 + threadIdx.x;   // E/4 threads
    int4 d4 = reinterpret_cast<const int4*>(ei + NEDGE)[i];
    atomicAdd(&hist[d4.x], 1);
    atomicAdd(&hist[d4.y], 1);
    atomicAdd(&hist[d4.z], 1);
    atomicAdd(&hist[d4.w], 1);
}

__global__ __launch_bounds__(256) void k_scan1(const int* __restrict__ hist,
                                               int* __restrict__ off,
                                               int* __restrict__ btot) {
    __shared__ int ts[256];
    int base = blockIdx.x * 1024 + threadIdx.x * 4;
    int4 v = *reinterpret_cast<const int4*>(hist + base);
    int s = v.x + v.y + v.z + v.w;
    ts[threadIdx.x] = s;
    __syncthreads();
    for (int d = 1; d < 256; d <<= 1) {
        int t = (threadIdx.x >= d) ? ts[threadIdx.x - d] : 0;
        __syncthreads();
        ts[threadIdx.x] += t;
        __syncthreads();
    }
    int excl = ts[threadIdx.x] - s;
    int4 o;
    o.x = excl; o.y = excl + v.x; o.z = o.y + v.y; o.w = o.z + v.z;
    *reinterpret_cast<int4*>(off + base) = o;
    if (threadIdx.x == 255) btot[blockIdx.x] = ts[255];
}

__global__ void k_scan2(int* __restrict__ btot) {
    __shared__ int ts[256];
    int v = (threadIdx.x < (N_NODES / 1024)) ? btot[threadIdx.x] : 0;
    ts[threadIdx.x] = v;
    __syncthreads();
    for (int d = 1; d < 256; d <<= 1) {
        int t = (threadIdx.x >= d) ? ts[threadIdx.x - d] : 0;
        __syncthreads();
        ts[threadIdx.x] += t;
        __syncthreads();
    }
    if (threadIdx.x < (N_NODES / 1024)) btot[threadIdx.x] = ts[threadIdx.x] - v;
}

__global__ __launch_bounds__(256) void k_scan3(int* __restrict__ off,
                                               const int* __restrict__ btot,
                                               int* __restrict__ cur) {
    int i = blockIdx.x * 256 + threadIdx.x;   // N threads
    int v = off[i] + btot[i >> 10];
    off[i] = v;
    cur[i] = v;
}

// XCD-ranged fill: blocks with bid%8==p handle dst in [p*N/8,(p+1)*N/8).
__global__ __launch_bounds__(256) void k_fill(const int* __restrict__ ei,
                                              int* __restrict__ cur,
                                              int* __restrict__ elist) {
    const int pass = blockIdx.x & 7;
    const int lo = pass * (N_NODES / NPASS);
    const int hi = lo + (N_NODES / NPASS);
    const int tid = (blockIdx.x >> 3) * 256 + threadIdx.x;   // 0..65535
    const int stride = (FILLB / NPASS) * 256;                // 65536
    const int E4 = NEDGE / 4;
    for (int i = tid; i < E4; i += stride) {
        int4 d4 = reinterpret_cast<const int4*>(ei + NEDGE)[i];
        bool m0 = (d4.x >= lo && d4.x < hi);
        bool m1 = (d4.y >= lo && d4.y < hi);
        bool m2 = (d4.z >= lo && d4.z < hi);
        bool m3 = (d4.w >= lo && d4.w < hi);
        if (!(m0 | m1 | m2 | m3)) continue;
        int4 s4 = reinterpret_cast<const int4*>(ei)[i];
        if (m0) elist[atomicAdd(&cur[d4.x], 1)] = s4.x;
        if (m1) elist[atomicAdd(&cur[d4.y], 1)] = s4.y;
        if (m2) elist[atomicAdd(&cur[d4.z], 1)] = s4.z;
        if (m3) elist[atomicAdd(&cur[d4.w], 1)] = s4.w;
    }
}

// ---------------- x (f32) -> xb (bf16) ----------------
__global__ __launch_bounds__(256) void k_xprep(const float* __restrict__ x,
                                               unsigned short* __restrict__ xb) {
    int i = blockIdx.x * 256 + threadIdx.x;   // N*64/8 threads
    float4 f0 = *reinterpret_cast<const float4*>(x + (size_t)i * 8);
    float4 f1 = *reinterpret_cast<const float4*>(x + (size_t)i * 8 + 4);
    uint4 u;
    u.x = f2bf(f0.x) | ((unsigned)f2bf(f0.y) << 16);
    u.y = f2bf(f0.z) | ((unsigned)f2bf(f0.w) << 16);
    u.z = f2bf(f1.x) | ((unsigned)f2bf(f1.y) << 16);
    u.w = f2bf(f1.z) | ((unsigned)f2bf(f1.w) << 16);
    *reinterpret_cast<uint4*>(xb + (size_t)i * 8) = u;
}

// agg[n] = sum of bf16 x rows over in-edges; 8 lanes/node, f32 accum, bf16 out
__global__ __launch_bounds__(256) void k_gather(const unsigned short* __restrict__ xb,
                                                const int* __restrict__ off,
                                                const int* __restrict__ hist,
                                                const int* __restrict__ elist,
                                                unsigned short* __restrict__ aggb) {
    int t = blockIdx.x * 256 + threadIdx.x;   // N*8 threads
    int n = t >> 3;
    int j = (t & 7) * 8;                      // channel base
    int start = off[n];
    int deg   = hist[n];
    float a[8];
    #pragma unroll
    for (int c = 0; c < 8; ++c) a[c] = 0.f;
    for (int i = 0; i < deg; ++i) {
        int s = elist[start + i];
        uint4 u = *reinterpret_cast<const uint4*>(xb + (size_t)s * IN_C + j);
        unsigned w[4] = {u.x, u.y, u.z, u.w};
        #pragma unroll
        for (int c = 0; c < 4; ++c) {
            a[2 * c]     += __builtin_bit_cast(float, w[c] << 16);
            a[2 * c + 1] += __builtin_bit_cast(float, w[c] & 0xffff0000u);
        }
    }
    uint4 o;
    o.x = f2bf(a[0]) | ((unsigned)f2bf(a[1]) << 16);
    o.y = f2bf(a[2]) | ((unsigned)f2bf(a[3]) << 16);
    o.z = f2bf(a[4]) | ((unsigned)f2bf(a[5]) << 16);
    o.w = f2bf(a[6]) | ((unsigned)f2bf(a[7]) << 16);
    *reinterpret_cast<uint4*>(aggb + (size_t)n * IN_C + j) = o;
}

// --- pack Wcat = [W_rel; W_root] (128x128, k-major) -> bf16 B-fragments [4][8][64][8] ---
__global__ __launch_bounds__(256) void k_wprep2(const float* __restrict__ Wrel,
                                                const float* __restrict__ Wroot,
                                                unsigned short* __restrict__ wG) {
    int i = blockIdx.x * 256 + threadIdx.x;   // 16384 threads
    int j    = i & 7;
    int lane = (i >> 3) & 63;
    int g    = (i >> 9) & 7;
    int ks   = i >> 12;
    int o    = g * 16 + (lane & 15);
    int k    = ks * 32 + ((lane >> 4) << 3) + j;
    float v = (k < IN_C) ? Wrel[k * OUT_C + o] : Wroot[(k - IN_C) * OUT_C + o];
    wG[i] = f2bf(v);
}

// ======== h = [agg||x] @ Wcat + b_rel via bf16 MFMA -> hb (bf16), fused BN1 stats ========
__global__ __launch_bounds__(256) void k_gemm1(const unsigned short* __restrict__ aggb,
                                               const unsigned short* __restrict__ xb,
                                               const unsigned short* __restrict__ wG,
                                               const float* __restrict__ brel,
                                               unsigned short* __restrict__ hb,
                                               float* __restrict__ sums) {
    __shared__ unsigned short tile[GM * 128];   // bf16 A-tile, XOR-swizzled, 32 KB
    __shared__ float red[2][OUT_C];
    const int n0 = blockIdx.x * GM;

    for (int i = threadIdx.x; i < 2 * OUT_C; i += 256) (&red[0][0])[i] = 0.f;

    // stage [aggb(64) || xb(64)] per node, straight uint4 copies + XOR swizzle
    for (int i = threadIdx.x; i < GM * 16; i += 256) {
        int t = i >> 4, s = i & 15;
        const unsigned short* src = (s < 8) ? (aggb + (size_t)(n0 + t) * IN_C + s * 8)
                                            : (xb   + (size_t)(n0 + t) * IN_C + (s - 8) * 8);
        uint4 u = *reinterpret_cast<const uint4*>(src);
        int byte = t * 256 + (((s ^ (t & 7)) & 15) << 4);
        *reinterpret_cast<uint4*>(reinterpret_cast<char*>(tile) + byte) = u;
    }
    __syncthreads();

    const int w    = threadIdx.x >> 6;    // wave -> rows [32w, 32w+32)
    const int lane = threadIdx.x & 63;
    const int r16  = lane & 15;
    const int kg   = lane >> 4;           // 0..3

    f32x4 acc[2][8];
    #pragma unroll
    for (int rs = 0; rs < 2; ++rs)
        #pragma unroll
        for (int g = 0; g < 8; ++g)
            acc[rs][g] = (f32x4){0.f, 0.f, 0.f, 0.f};

    for (int ks = 0; ks < 4; ++ks) {
        bf16x8 a[2];
        #pragma unroll
        for (int rs = 0; rs < 2; ++rs) {
            const int t = w * 32 + rs * 16 + r16;
            const int slot = ks * 4 + kg;
            const int byte = t * 256 + (((slot ^ (t & 7)) & 15) << 4);
            uint4 u = *reinterpret_cast<const uint4*>(reinterpret_cast<const char*>(tile) + byte);
            a[rs] = __builtin_bit_cast(bf16x8, u);
        }
        #pragma unroll
        for (int g = 0; g < 8; ++g) {
            uint4 u = *reinterpret_cast<const uint4*>(wG + (((ks * 8 + g) * 64 + lane) << 3));
            bf16x8 b = __builtin_bit_cast(bf16x8, u);
            acc[0][g] = __builtin_amdgcn_mfma_f32_16x16x32_bf16(a[0], b, acc[0][g], 0, 0, 0);
            acc[1][g] = __builtin_amdgcn_mfma_f32_16x16x32_bf16(a[1], b, acc[1][g], 0, 0, 0);
        }
    }

    // epilogue: bias, store hb bf16, fused BN1 stats (f32-exact)
    #pragma unroll
    for (int g = 0; g < 8; ++g) {
        const int col = g * 16 + r16;
        const float bias = brel[col];
        float s = 0.f, q = 0.f;
        #pragma unroll
        for (int rs = 0; rs < 2; ++rs) {
            #pragma unroll
            for (int reg = 0; reg < 4; ++reg) {
                const int row = n0 + w * 32 + rs * 16 + kg * 4 + reg;
                float v = acc[rs][g][reg] + bias;
                hb[(size_t)row * OUT_C + col] = f2bf(v);
                s += v;
                q += v * v;
            }
        }
        atomicAdd(&red[0][col], s);
        atomicAdd(&red[1][col], q);
    }
    __syncthreads();
    if (threadIdx.x < OUT_C) {
        atomicAdd(&sums[threadIdx.x], red[0][threadIdx.x]);
        atomicAdd(&sums[OUT_C + threadIdx.x], red[1][threadIdx.x]);
    }
}

// ---------------- BN scale/shift from sums ----------------
__global__ void k_bnparams(const float* __restrict__ sums,
                           const float* __restrict__ g,
                           const float* __restrict__ b,
                           float* __restrict__ sc, float* __restrict__ sh) {
    int c = threadIdx.x;   // 128 threads
    const float inv_n = 1.0f / (float)N_NODES;
    float mean = sums[c] * inv_n;
    float var  = sums[OUT_C + c] * inv_n - mean * mean;
    float s = g[c] * rsqrtf(var + EPSV);
    sc[c] = s;
    sh[c] = b[c] - mean * s;
}

// ----- pack conv_w [O][CI][KW] f32 -> bf16 B-fragments [12][8][64][8] -----
__global__ __launch_bounds__(256) void k_wprep(const float* __restrict__ w,
                                               unsigned short* __restrict__ wBf) {
    int i = blockIdx.x * 256 + threadIdx.x;   // 49152 threads
    int j    = i & 7;
    int lane = (i >> 3) & 63;
    int g    = (i >> 9) & 7;
    int ks   = i >> 12;
    int o    = g * 16 + (lane & 15);
    int ci   = (ks & 3) * 32 + ((lane >> 4) << 3) + j;
    int ktap = ks >> 2;
    wBf[i] = f2bf(w[o * (OUT_C * KW) + ci * KW + ktap]);
}

// ----- pack res_w [128][64] -> bf16 B-fragments [2][8][64][8] -----
__global__ __launch_bounds__(256) void k_wprep3(const float* __restrict__ rw,
                                                unsigned short* __restrict__ wR) {
    int i = blockIdx.x * 256 + threadIdx.x;   // 8192 threads
    int j    = i & 7;
    int lane = (i >> 3) & 63;
    int g    = (i >> 9) & 7;
    int ks   = i >> 12;                        // 0..1
    int o    = g * 16 + (lane & 15);
    int k    = ks * 32 + ((lane >> 4) << 3) + j;
    wR[i] = f2bf(rw[o * IN_C + k]);
}

// ------- Conv1d via bf16 MFMA: hb (bf16) in, BN1+ReLU at staging, cbuf (bf16) out, BN2 stats fused -------
__global__ __launch_bounds__(256) void k_conv(const unsigned short* __restrict__ hb,
                                              const unsigned short* __restrict__ wBf,
                                              const float* __restrict__ cbv,
                                              const float* __restrict__ sc,
                                              const float* __restrict__ sh,
                                              unsigned short* __restrict__ cbuf,
                                              float* __restrict__ sums) {
    __shared__ unsigned short tile[(LCH + 2) * OUT_C];   // bf16, XOR-swizzled, 16.9 KB
    __shared__ float red[2][OUT_C];
    const int b  = blockIdx.x >> 3;
    const int ch = blockIdx.x & 7;
    const int l0 = ch * LCH;
    const unsigned short* hbp = hb + (size_t)b * NLM * OUT_C;

    for (int i = threadIdx.x; i < 2 * OUT_C; i += 256) (&red[0][0])[i] = 0.f;

    // stage rows l0-1 .. l0+64: bf16 load, BN1+ReLU, re-round, XOR swizzle
    for (int i = threadIdx.x; i < (LCH + 2) * 16; i += 256) {
        int t = i >> 4;
        int s = i & 15;
        int l = l0 - 1 + t;
        uint4 u = make_uint4(0u, 0u, 0u, 0u);
        if (l >= 0 && l < NLM) {
            uint4 r = *reinterpret_cast<const uint4*>(hbp + (size_t)l * OUT_C + s * 8);
            unsigned wd[4] = {r.x, r.y, r.z, r.w};
            unsigned od[4];
            #pragma unroll
            for (int c2 = 0; c2 < 4; ++c2) {
                int c = s * 8 + c2 * 2;
                float lo = __builtin_bit_cast(float, wd[c2] << 16);
                float hi = __builtin_bit_cast(float, wd[c2] & 0xffff0000u);
                lo = fmaxf(0.f, lo * sc[c] + sh[c]);
                hi = fmaxf(0.f, hi * sc[c + 1] + sh[c + 1]);
                od[c2] = f2bf(lo) | ((unsigned)f2bf(hi) << 16);
            }
            u = make_uint4(od[0], od[1], od[2], od[3]);
        }
        int byte = t * 256 + (((s ^ (t & 7)) & 15) << 4);
        *reinterpret_cast<uint4*>(reinterpret_cast<char*>(tile) + byte) = u;
    }
    __syncthreads();

    const int w    = threadIdx.x >> 6;    // wave 0..3 -> out cols [32w, 32w+32)
    const int lane = threadIdx.x & 63;
    const int r16  = lane & 15;
    const int kg   = lane >> 4;           // 0..3

    f32x4 acc[4][2];
    #pragma unroll
    for (int rs = 0; rs < 4; ++rs)
        #pragma unroll
        for (int cs = 0; cs < 2; ++cs)
            acc[rs][cs] = (f32x4){0.f, 0.f, 0.f, 0.f};

    for (int ks = 0; ks < 12; ++ks) {
        const int ktap = ks >> 2;
        const int slotbase = (ks & 3) * 4 + kg;
        bf16x8 bfr[2];
        #pragma unroll
        for (int cs = 0; cs < 2; ++cs) {
            const int g = w * 2 + cs;
            uint4 u = *reinterpret_cast<const uint4*>(wBf + (((ks * 8 + g) * 64 + lane) << 3));
            bfr[cs] = __builtin_bit_cast(bf16x8, u);
        }
        #pragma unroll
        for (int rs = 0; rs < 4; ++rs) {
            const int t = rs * 16 + r16 + ktap;
            const int byte = t * 256 + (((slotbase ^ (t & 7)) & 15) << 4);
            uint4 u = *reinterpret_cast<const uint4*>(reinterpret_cast<const char*>(tile) + byte);
            bf16x8 af = __builtin_bit_cast(bf16x8, u);
            acc[rs][0] = __builtin_amdgcn_mfma_f32_16x16x32_bf16(af, bfr[0], acc[rs][0], 0, 0, 0);
            acc[rs][1] = __builtin_amdgcn_mfma_f32_16x16x32_bf16(af, bfr[1], acc[rs][1], 0, 0, 0);
        }
    }

    #pragma unroll
    for (int cs = 0; cs < 2; ++cs) {
        const int col = w * 32 + cs * 16 + r16;
        const float bias = cbv[col];
        float s = 0.f, q = 0.f;
        #pragma unroll
        for (int rs = 0; rs < 4; ++rs) {
            #pragma unroll
            for (int reg = 0; reg < 4; ++reg) {
                int l = l0 + rs * 16 + kg * 4 + reg;
                if (l < NLM) {
                    float v = acc[rs][cs][reg] + bias;
                    cbuf[((size_t)b * NLM + l) * OUT_C + col] = f2bf(v);
                    s += v;
                    q += v * v;
                }
            }
        }
        atomicAdd(&red[0][col], s);
        atomicAdd(&red[1][col], q);
    }
    __syncthreads();
    if (threadIdx.x < OUT_C) {
        atomicAdd(&sums[threadIdx.x], red[0][threadIdx.x]);
        atomicAdd(&sums[OUT_C + threadIdx.x], red[1][threadIdx.x]);
    }
}

// ---- final: residual = xb @ wR via MFMA; out = BN2+ReLU(cbuf) + residual + rb ----
__global__ __launch_bounds__(256) void k_final(const unsigned short* __restrict__ cbuf,
                                               const unsigned short* __restrict__ xb,
                                               const unsigned short* __restrict__ wR,
                                               const float* __restrict__ rb,
                                               const float* __restrict__ sc,
                                               const float* __restrict__ sh,
                                               float* __restrict__ out) {
    __shared__ unsigned short tile[GM * IN_C];   // 128 x 64 bf16, 16 KB
    const int n0 = blockIdx.x * GM;

    for (int i = threadIdx.x; i < GM * 8; i += 256) {
        int t = i >> 3, s = i & 7;
        uint4 u = *reinterpret_cast<const uint4*>(xb + (size_t)(n0 + t) * IN_C + s * 8);
        int byte = t * 128 + (((s ^ (t & 7)) & 7) << 4);
        *reinterpret_cast<uint4*>(reinterpret_cast<char*>(tile) + byte) = u;
    }
    __syncthreads();

    const int w    = threadIdx.x >> 6;
    const int lane = threadIdx.x & 63;
    const int r16  = lane & 15;
    const int kg   = lane >> 4;

    f32x4 acc[2][8];
    #pragma unroll
    for (int rs = 0; rs < 2; ++rs)
        #pragma unroll
        for (int g = 0; g < 8; ++g)
            acc[rs][g] = (f32x4){0.f, 0.f, 0.f, 0.f};

    #pragma unroll
    for (int ks = 0; ks < 2; ++ks) {
        bf16x8 a[2];
        #pragma unroll
        for (int rs = 0; rs < 2; ++rs) {
            const int t = w * 32 + rs * 16 + r16;
            const int slot = ks * 4 + kg;
            const int byte = t * 128 + (((slot ^ (t & 7)) & 7) << 4);
            uint4 u = *reinterpret_cast<const uint4*>(reinterpret_cast<const char*>(tile) + byte);
            a[rs] = __builtin_bit_cast(bf16x8, u);
        }
        #pragma unroll
        for (int g = 0; g < 8; ++g) {
            uint4 u = *reinterpret_cast<const uint4*>(wR + (((ks * 8 + g) * 64 + lane) << 3));
            bf16x8 b = __builtin_bit_cast(bf16x8, u);
            acc[0][g] = __builtin_amdgcn_mfma_f32_16x16x32_bf16(a[0], b, acc[0][g], 0, 0, 0);
            acc[1][g] = __builtin_amdgcn_mfma_f32_16x16x32_bf16(a[1], b, acc[1][g], 0, 0, 0);
        }
    }

    #pragma unroll
    for (int g = 0; g < 8; ++g) {
        const int col = g * 16 + r16;
        const float bias = rb[col];
        const float scv = sc[col];
        const float shv = sh[col];
        #pragma unroll
        for (int rs = 0; rs < 2; ++rs) {
            #pragma unroll
            for (int reg = 0; reg < 4; ++reg) {
                const size_t row = (size_t)(n0 + w * 32 + rs * 16 + kg * 4 + reg);
                float cv = bf2f(cbuf[row * OUT_C + col]);
                out[row * OUT_C + col] = fmaxf(0.f, cv * scv + shv) + acc[rs][g][reg] + bias;
            }
        }
    }
}

extern "C" void kernel_launch(void* const* d_in, const int* in_sizes, int n_in,
                              void* d_out, int out_size, void* d_ws, size_t ws_size,
                              hipStream_t stream) {
    const float* x     = (const float*)d_in[0];
    const int*   ei    = (const int*)d_in[1];
    const float* Wrel  = (const float*)d_in[3];
    const float* brel  = (const float*)d_in[4];
    const float* Wroot = (const float*)d_in[5];
    const float* bn1g  = (const float*)d_in[6];
    const float* bn1b  = (const float*)d_in[7];
    const float* convw = (const float*)d_in[8];
    const float* convb = (const float*)d_in[9];
    const float* bn2g  = (const float*)d_in[10];
    const float* bn2b  = (const float*)d_in[11];
    const float* resw  = (const float*)d_in[12];
    const float* resb  = (const float*)d_in[13];
    float* out = (float*)d_out;

    unsigned short* aggb = (unsigned short*)d_ws;             // N*64 bf16 (30.7 MB)
    unsigned short* xb   = aggb + (size_t)N_NODES * IN_C;     // N*64 bf16 (30.7 MB)
    unsigned short* hb   = xb + (size_t)N_NODES * IN_C;       // N*128 bf16 (61.3 MB)
    unsigned short* cbuf = hb + (size_t)N_NODES * OUT_C;      // N*128 bf16 (61.3 MB)
    float* st = (float*)(cbuf + (size_t)N_NODES * OUT_C);     // small tail
    float* sums1 = st;        float* sc1 = st + 256; float* sh1 = st + 384;
    float* sums2 = st + 512;  float* sc2 = st + 768; float* sh2 = st + 896;
    unsigned short* wBf = (unsigned short*)(st + 1024);       // 49152 bf16 (96 KB)
    unsigned short* wG  = wBf + 49152;                        // 16384 bf16 (32 KB)
    unsigned short* wR  = wG + 16384;                         // 8192 bf16 (16 KB)

    // CSR arrays live inside hb's memory: hb is only written AFTER the gather.
    int* hist  = (int*)hb;
    int* off   = hist + N_NODES;
    int* cur   = off + N_NODES;
    int* btot  = cur + N_NODES;
    int* elist = btot + 256;          // E ints; total 18.2 MB << 61.3 MB

    hipMemsetAsync(hist, 0, (size_t)N_NODES * sizeof(int), stream);
    hipMemsetAsync(st, 0, 1024 * sizeof(float), stream);

    k_xprep <<<N_NODES / 32, 256, 0, stream>>>(x, xb);
    k_wprep <<<192, 256, 0, stream>>>(convw, wBf);
    k_wprep2<<<64, 256, 0, stream>>>(Wrel, Wroot, wG);
    k_wprep3<<<32, 256, 0, stream>>>(resw, wR);
    k_hist  <<<NEDGE / 1024, 256, 0, stream>>>(ei, hist);
    k_scan1 <<<N_NODES / 1024, 256, 0, stream>>>(hist, off, btot);
    k_scan2 <<<1, 256, 0, stream>>>(btot);
    k_scan3 <<<N_NODES / 256, 256, 0, stream>>>(off, btot, cur);
    k_fill  <<<FILLB, 256, 0, stream>>>(ei, cur, elist);
    k_gather<<<(N_NODES * 8) / 256, 256, 0, stream>>>(xb, off, hist, elist, aggb);

    k_gemm1<<<N_NODES / GM, 256, 0, stream>>>(aggb, xb, wG, brel, hb, sums1);
    k_bnparams<<<1, 128, 0, stream>>>(sums1, bn1g, bn1b, sc1, sh1);
    k_conv<<<BSZ * NCH, 256, 0, stream>>>(hb, wBf, convb, sc1, sh1, cbuf, sums2);
    k_bnparams<<<1, 128, 0, stream>>>(sums2, bn2g, bn2b, sc2, sh2);
    k_final<<<N_NODES / GM, 256, 0, stream>>>(cbuf, xb, wR, resb, sc2, sh2, out);
}